// Round 2
// baseline (350.917 us; speedup 1.0000x reference)
//
#include <hip/hip_runtime.h>

// Rayleigh-Benard tendency kernel, fp32 I/O, fp32 math.
// Layout: state[6][NX][NY][NZ], z contiguous.
// Each thread handles 4 consecutive z via float4; z-neighbors via wave shuffles.
//
// R2: liveness restructure — each output is computed and stored immediately
// after its field's stencil phase, so at most one neighbor set (+ pressure
// gradients) is live at a time. __launch_bounds__(256,4) caps VGPR at 128
// (4 waves/SIMD). Outputs use nontemporal stores (pure streaming, no reuse)
// via a native ext_vector_type wrapper (HIP float4* is rejected by the builtin).

namespace {
constexpr int NXc = 256, NYc = 256, NZc = 128;
constexpr int FS = NXc * NYc * NZc;   // field stride (elements)
constexpr int XS = NYc * NZc;         // x stride
constexpr int YS = NZc;               // y stride

constexpr float MUc = 1.8e-5f, KTHc = 0.025f, Gc = 9.8f;
constexpr float Rgas = 287.0f;        // CP - CV
constexpr float invCV = 1.0f / 717.0f;

// DX=1/256, DY=1/256, DZ=1/127 — exact in fp32
constexpr float inv2dx = 128.0f, inv2dy = 128.0f, inv2dz = 63.5f;
constexpr float invdx2 = 65536.0f, invdy2 = 65536.0f, invdz2 = 16129.0f;

typedef float nf4 __attribute__((ext_vector_type(4)));
}

__device__ __forceinline__ float4 ld4(const float* __restrict__ p, int i4) {
    return reinterpret_cast<const float4*>(p)[i4];
}

__device__ __forceinline__ void st_nt(float4 v, float4* p) {
    nf4 nv;
    nv.x = v.x; nv.y = v.y; nv.z = v.z; nv.w = v.w;
    __builtin_nontemporal_store(nv, reinterpret_cast<nf4*>(p));
}

// Loads 4 neighbor float4s for field q and fetches z-halo scalars via shuffle.
#define LOADN(q, sq) \
    const float4 q##_xm = ld4(sq, bxm4), q##_xp = ld4(sq, bxp4); \
    const float4 q##_ym = ld4(sq, bym4), q##_yp = ld4(sq, byp4); \
    const float q##_zm = __shfl_up(q##_c.w, 1, 32); \
    const float q##_zp = __shfl_down(q##_c.x, 1, 32);

// Advection + Laplacian for one component C with z-neighbors PREV/NEXT.
#define ADV_LAP_C(q, C, PREV, NEXT) \
    adv_##q.C = u_c.C * (q##_xp.C - q##_xm.C) * inv2dx \
              + v_c.C * (q##_yp.C - q##_ym.C) * inv2dy \
              + w_c.C * ((NEXT) - (PREV)) * inv2dz; \
    lap_##q.C = (q##_xp.C + q##_xm.C - 2.0f * q##_c.C) * invdx2 \
              + (q##_yp.C + q##_ym.C - 2.0f * q##_c.C) * invdy2 \
              + ((NEXT) + (PREV) - 2.0f * q##_c.C) * invdz2;

#define DERIVS(q) \
    float4 adv_##q, lap_##q; \
    ADV_LAP_C(q, x, q##_zm,  q##_c.y) \
    ADV_LAP_C(q, y, q##_c.x, q##_c.z) \
    ADV_LAP_C(q, z, q##_c.y, q##_c.w) \
    ADV_LAP_C(q, w, q##_c.z, q##_zp)

__global__ __launch_bounds__(256, 4) void rb_kernel(const float* __restrict__ s,
                                                    float* __restrict__ o) {
    const int l = threadIdx.x;                    // z-quad index 0..31 (lanes)
    const int y = blockIdx.x * 8 + threadIdx.y;   // 0..255
    const int x = blockIdx.y;                     // 0..255

    const int xm = (x == 0) ? NXc - 1 : x - 1;
    const int xp = (x == NXc - 1) ? 0 : x + 1;
    const int ym = (y == 0) ? NYc - 1 : y - 1;
    const int yp = (y == NYc - 1) ? 0 : y + 1;

    const int b4   = (x * XS + y * YS) / 4 + l;
    const int bxm4 = (xm * XS + y * YS) / 4 + l;
    const int bxp4 = (xp * XS + y * YS) / 4 + l;
    const int bym4 = (x * XS + ym * YS) / 4 + l;
    const int byp4 = (x * XS + yp * YS) / 4 + l;

    const float* su = s;
    const float* sv = s + FS;
    const float* sw = s + 2 * FS;
    const float* sr = s + 3 * FS;
    const float* st = s + 4 * FS;
    const float* sc = s + 5 * FS;

    float4* o4 = reinterpret_cast<float4*>(o);
    const int fs4 = FS / 4;

    const float4 u_c = ld4(su, b4), v_c = ld4(sv, b4), w_c = ld4(sw, b4);
    const float4 r_c = ld4(sr, b4), T_c = ld4(st, b4), c_c = ld4(sc, b4);

    float4 inv_r;
    inv_r.x = 1.0f / r_c.x; inv_r.y = 1.0f / r_c.y;
    inv_r.z = 1.0f / r_c.z; inv_r.w = 1.0f / r_c.w;

    // ---- Phase 1: T + r neighbors -> pressure gradients, dT ----
    LOADN(T, st)
    LOADN(r, sr)

    float4 p_c, p_xm, p_xp, p_ym, p_yp;
#define PC(C) \
    p_c.C  = Rgas * r_c.C  * T_c.C; \
    p_xm.C = Rgas * r_xm.C * T_xm.C;  p_xp.C = Rgas * r_xp.C * T_xp.C; \
    p_ym.C = Rgas * r_ym.C * T_ym.C;  p_yp.C = Rgas * r_yp.C * T_yp.C;
    PC(x) PC(y) PC(z) PC(w)
#undef PC
    const float p_zm = __shfl_up(p_c.w, 1, 32);
    const float p_zp = __shfl_down(p_c.x, 1, 32);

    float4 dpdx, dpdy, dpdz;
#define DP(C) \
    dpdx.C = (p_xp.C - p_xm.C) * inv2dx; \
    dpdy.C = (p_yp.C - p_ym.C) * inv2dy;
    DP(x) DP(y) DP(z) DP(w)
#undef DP
    dpdz.x = (p_c.y - p_zm) * inv2dz;
    dpdz.y = (p_c.z - p_c.x) * inv2dz;
    dpdz.z = (p_c.w - p_c.y) * inv2dz;
    dpdz.w = (p_zp  - p_c.z) * inv2dz;

    {
        DERIVS(T)
        float4 dT4;
        dT4.x = KTHc * lap_T.x * inv_r.x * invCV - adv_T.x;
        dT4.y = KTHc * lap_T.y * inv_r.y * invCV - adv_T.y;
        dT4.z = KTHc * lap_T.z * inv_r.z * invCV - adv_T.z;
        dT4.w = KTHc * lap_T.w * inv_r.w * invCV - adv_T.w;
        if (l == 0)  dT4.x = 0.0f;
        if (l == 31) dT4.w = 0.0f;
        st_nt(dT4, o4 + b4 + 4 * fs4);
    }

    // ---- Phase 2: u -> du, drou (needs r_x* which stay live from phase 1) ----
    {
        LOADN(u, su)
        DERIVS(u)
        float4 du4, drou;
#define OUTU(C) \
        du4.C  = (-dpdx.C + MUc * lap_u.C) * inv_r.C - adv_u.C; \
        drou.C = -(r_xp.C * u_xp.C - r_xm.C * u_xm.C) * inv2dx;
        OUTU(x) OUTU(y) OUTU(z) OUTU(w)
#undef OUTU
        if (l == 0)  du4.x = 0.0f;
        if (l == 31) du4.w = 0.0f;
        st_nt(du4,  o4 + b4);
        st_nt(drou, o4 + b4 + 3 * fs4);
    }

    // ---- Phase 3: v -> dv ----
    {
        LOADN(v, sv)
        DERIVS(v)
        float4 dv4;
        dv4.x = (-dpdy.x + MUc * lap_v.x) * inv_r.x - adv_v.x;
        dv4.y = (-dpdy.y + MUc * lap_v.y) * inv_r.y - adv_v.y;
        dv4.z = (-dpdy.z + MUc * lap_v.z) * inv_r.z - adv_v.z;
        dv4.w = (-dpdy.w + MUc * lap_v.w) * inv_r.w - adv_v.w;
        if (l == 0)  dv4.x = 0.0f;
        if (l == 31) dv4.w = 0.0f;
        st_nt(dv4, o4 + b4 + fs4);
    }

    // ---- Phase 4: w -> dw ----
    {
        LOADN(w, sw)
        DERIVS(w)
        float4 dw4;
        dw4.x = (-Gc * r_c.x - dpdz.x + MUc * lap_w.x) * inv_r.x - adv_w.x;
        dw4.y = (-Gc * r_c.y - dpdz.y + MUc * lap_w.y) * inv_r.y - adv_w.y;
        dw4.z = (-Gc * r_c.z - dpdz.z + MUc * lap_w.z) * inv_r.z - adv_w.z;
        dw4.w = (-Gc * r_c.w - dpdz.w + MUc * lap_w.w) * inv_r.w - adv_w.w;
        if (l == 0)  dw4.x = 0.0f;
        if (l == 31) dw4.w = 0.0f;
        st_nt(dw4, o4 + b4 + 2 * fs4);
    }

    // ---- Phase 5: c -> dc (advection only) ----
    {
        LOADN(c, sc)
        float4 dc4;
#define DC(C, PREV, NEXT) \
        dc4.C = -(u_c.C * (c_xp.C - c_xm.C) * inv2dx \
                + v_c.C * (c_yp.C - c_ym.C) * inv2dy \
                + w_c.C * ((NEXT) - (PREV)) * inv2dz);
        DC(x, c_zm,  c_c.y)
        DC(y, c_c.x, c_c.z)
        DC(z, c_c.y, c_c.w)
        DC(w, c_c.z, c_zp)
#undef DC
        // z-wall fixes: lane 0 comp .x is z=0, lane 31 comp .w is z=127
        if (l == 0) {
            const float dzc0 = (-3.0f * c_c.x + 4.0f * c_c.y - c_c.z) * inv2dz;
            dc4.x = -(u_c.x * (c_xp.x - c_xm.x) * inv2dx
                    + v_c.x * (c_yp.x - c_ym.x) * inv2dy
                    + w_c.x * dzc0);
        }
        if (l == 31) {
            const float dzcN = (3.0f * c_c.w - 4.0f * c_c.z + c_c.y) * inv2dz;
            dc4.w = -(u_c.w * (c_xp.w - c_xm.w) * inv2dx
                    + v_c.w * (c_yp.w - c_ym.w) * inv2dy
                    + w_c.w * dzcN);
        }
        st_nt(dc4, o4 + b4 + 5 * fs4);
    }
}

extern "C" void kernel_launch(void* const* d_in, const int* in_sizes, int n_in,
                              void* d_out, int out_size, void* d_ws, size_t ws_size,
                              hipStream_t stream) {
    (void)in_sizes; (void)n_in; (void)d_ws; (void)ws_size; (void)out_size;
    const float* s = (const float*)d_in[0];
    float* o = (float*)d_out;

    dim3 block(32, 8, 1);         // 32 z-quads (lanes) x 8 y rows = 256 threads
    dim3 grid(NYc / 8, NXc, 1);   // (y tiles, x)
    rb_kernel<<<grid, block, 0, stream>>>(s, o);
}

// Round 3
// 343.741 us; speedup vs baseline: 1.0209x; 1.0209x over previous
//
#include <hip/hip_runtime.h>

// Rayleigh-Benard tendency kernel, fp32 I/O, fp32 math.
// Layout: state[6][NX][NY][NZ], z contiguous.
// Each thread handles 4 consecutive z via float4; z-neighbors via wave shuffles.
//
// R3: revert R2's phase-scoped liveness restructure (it let the compiler find a
// 64-VGPR fully-serialized schedule: MLP collapsed, 130 us vs 105 us). Back to
// the single-scope structure (compiler keeps ~30 loads in flight), keep NT
// stores but ALL AT THE END so store-vmcnt never gates a load wait (stores and
// loads share vmcnt on CDNA). No min-waves hint: ILP > occupancy here.

namespace {
constexpr int NXc = 256, NYc = 256, NZc = 128;
constexpr int FS = NXc * NYc * NZc;   // field stride (elements)
constexpr int XS = NYc * NZc;         // x stride
constexpr int YS = NZc;               // y stride

constexpr float MUc = 1.8e-5f, KTHc = 0.025f, Gc = 9.8f;
constexpr float Rgas = 287.0f;        // CP - CV
constexpr float invCV = 1.0f / 717.0f;

// DX=1/256, DY=1/256, DZ=1/127 — exact in fp32
constexpr float inv2dx = 128.0f, inv2dy = 128.0f, inv2dz = 63.5f;
constexpr float invdx2 = 65536.0f, invdy2 = 65536.0f, invdz2 = 16129.0f;

typedef float nf4 __attribute__((ext_vector_type(4)));
}

__device__ __forceinline__ float4 ld4(const float* __restrict__ p, int i4) {
    return reinterpret_cast<const float4*>(p)[i4];
}

__device__ __forceinline__ void st_nt(float4 v, float4* p) {
    nf4 nv;
    nv.x = v.x; nv.y = v.y; nv.z = v.z; nv.w = v.w;
    __builtin_nontemporal_store(nv, reinterpret_cast<nf4*>(p));
}

// Loads 4 neighbor float4s for field q and fetches z-halo scalars via shuffle.
#define LOADN(q, sq) \
    const float4 q##_xm = ld4(sq, bxm4), q##_xp = ld4(sq, bxp4); \
    const float4 q##_ym = ld4(sq, bym4), q##_yp = ld4(sq, byp4); \
    const float q##_zm = __shfl_up(q##_c.w, 1, 32); \
    const float q##_zp = __shfl_down(q##_c.x, 1, 32);

// Advection + Laplacian for one component C with z-neighbors PREV/NEXT.
#define ADV_LAP_C(q, C, PREV, NEXT) \
    adv_##q.C = u_c.C * (q##_xp.C - q##_xm.C) * inv2dx \
              + v_c.C * (q##_yp.C - q##_ym.C) * inv2dy \
              + w_c.C * ((NEXT) - (PREV)) * inv2dz; \
    lap_##q.C = (q##_xp.C + q##_xm.C - 2.0f * q##_c.C) * invdx2 \
              + (q##_yp.C + q##_ym.C - 2.0f * q##_c.C) * invdy2 \
              + ((NEXT) + (PREV) - 2.0f * q##_c.C) * invdz2;

#define DERIVS(q) \
    float4 adv_##q, lap_##q; \
    ADV_LAP_C(q, x, q##_zm,  q##_c.y) \
    ADV_LAP_C(q, y, q##_c.x, q##_c.z) \
    ADV_LAP_C(q, z, q##_c.y, q##_c.w) \
    ADV_LAP_C(q, w, q##_c.z, q##_zp)

__global__ __launch_bounds__(256) void rb_kernel(const float* __restrict__ s,
                                                 float* __restrict__ o) {
    const int l = threadIdx.x;                    // z-quad index 0..31 (lanes)
    const int y = blockIdx.x * 8 + threadIdx.y;   // 0..255
    const int x = blockIdx.y;                     // 0..255

    const int xm = (x == 0) ? NXc - 1 : x - 1;
    const int xp = (x == NXc - 1) ? 0 : x + 1;
    const int ym = (y == 0) ? NYc - 1 : y - 1;
    const int yp = (y == NYc - 1) ? 0 : y + 1;

    const int b4   = (x * XS + y * YS) / 4 + l;
    const int bxm4 = (xm * XS + y * YS) / 4 + l;
    const int bxp4 = (xp * XS + y * YS) / 4 + l;
    const int bym4 = (x * XS + ym * YS) / 4 + l;
    const int byp4 = (x * XS + yp * YS) / 4 + l;

    const float* su = s;
    const float* sv = s + FS;
    const float* sw = s + 2 * FS;
    const float* sr = s + 3 * FS;
    const float* st = s + 4 * FS;
    const float* sc = s + 5 * FS;

    const float4 u_c = ld4(su, b4), v_c = ld4(sv, b4), w_c = ld4(sw, b4);
    const float4 r_c = ld4(sr, b4), T_c = ld4(st, b4), c_c = ld4(sc, b4);

    float4 inv_r;
    inv_r.x = 1.0f / r_c.x; inv_r.y = 1.0f / r_c.y;
    inv_r.z = 1.0f / r_c.z; inv_r.w = 1.0f / r_c.w;

    // ---- T (stencil) and pressure gradients ----
    LOADN(T, st)
    DERIVS(T)
    LOADN(r, sr)

    float4 p_c, p_xm, p_xp, p_ym, p_yp;
#define PC(C) \
    p_c.C  = Rgas * r_c.C  * T_c.C; \
    p_xm.C = Rgas * r_xm.C * T_xm.C;  p_xp.C = Rgas * r_xp.C * T_xp.C; \
    p_ym.C = Rgas * r_ym.C * T_ym.C;  p_yp.C = Rgas * r_yp.C * T_yp.C;
    PC(x) PC(y) PC(z) PC(w)
#undef PC
    const float p_zm = __shfl_up(p_c.w, 1, 32);
    const float p_zp = __shfl_down(p_c.x, 1, 32);

    float4 dpdx, dpdy, dpdz;
#define DP(C) \
    dpdx.C = (p_xp.C - p_xm.C) * inv2dx; \
    dpdy.C = (p_yp.C - p_ym.C) * inv2dy;
    DP(x) DP(y) DP(z) DP(w)
#undef DP
    dpdz.x = (p_c.y - p_zm) * inv2dz;
    dpdz.y = (p_c.z - p_c.x) * inv2dz;
    dpdz.z = (p_c.w - p_c.y) * inv2dz;
    dpdz.w = (p_zp  - p_c.z) * inv2dz;

    // ---- u (+ drou, which needs r_x* and u_x*) ----
    LOADN(u, su)
    DERIVS(u)
    float4 drou;
#define DR(C) drou.C = -(r_xp.C * u_xp.C - r_xm.C * u_xm.C) * inv2dx;
    DR(x) DR(y) DR(z) DR(w)
#undef DR

    // ---- v ----
    LOADN(v, sv)
    DERIVS(v)

    // ---- w ----
    LOADN(w, sw)
    DERIVS(w)

    // ---- c (advection only; lap_c is dead code, DCE'd) ----
    LOADN(c, sc)
    DERIVS(c)
    (void)lap_c;

    float4 du4, dv4, dw4, dT4, dc4;
#define OUT(C) \
    du4.C = (-dpdx.C + MUc * lap_u.C) * inv_r.C - adv_u.C; \
    dv4.C = (-dpdy.C + MUc * lap_v.C) * inv_r.C - adv_v.C; \
    dw4.C = (-Gc * r_c.C - dpdz.C + MUc * lap_w.C) * inv_r.C - adv_w.C; \
    dT4.C = KTHc * lap_T.C * inv_r.C * invCV - adv_T.C; \
    dc4.C = -adv_c.C;
    OUT(x) OUT(y) OUT(z) OUT(w)
#undef OUT

    // z-wall fixes: lane 0 comp .x is z=0, lane 31 comp .w is z=127
    if (l == 0) {
        du4.x = 0.0f; dv4.x = 0.0f; dw4.x = 0.0f; dT4.x = 0.0f;
        const float dzc0 = (-3.0f * c_c.x + 4.0f * c_c.y - c_c.z) * inv2dz;
        dc4.x = -(u_c.x * (c_xp.x - c_xm.x) * inv2dx
                + v_c.x * (c_yp.x - c_ym.x) * inv2dy
                + w_c.x * dzc0);
    }
    if (l == 31) {
        du4.w = 0.0f; dv4.w = 0.0f; dw4.w = 0.0f; dT4.w = 0.0f;
        const float dzcN = (3.0f * c_c.w - 4.0f * c_c.z + c_c.y) * inv2dz;
        dc4.w = -(u_c.w * (c_xp.w - c_xm.w) * inv2dx
                + v_c.w * (c_yp.w - c_ym.w) * inv2dy
                + w_c.w * dzcN);
    }

    float4* o4 = reinterpret_cast<float4*>(o);
    const int fs4 = FS / 4;
    st_nt(du4,  o4 + b4);
    st_nt(dv4,  o4 + b4 + fs4);
    st_nt(dw4,  o4 + b4 + 2 * fs4);
    st_nt(drou, o4 + b4 + 3 * fs4);
    st_nt(dT4,  o4 + b4 + 4 * fs4);
    st_nt(dc4,  o4 + b4 + 5 * fs4);
}

extern "C" void kernel_launch(void* const* d_in, const int* in_sizes, int n_in,
                              void* d_out, int out_size, void* d_ws, size_t ws_size,
                              hipStream_t stream) {
    (void)in_sizes; (void)n_in; (void)d_ws; (void)ws_size; (void)out_size;
    const float* s = (const float*)d_in[0];
    float* o = (float*)d_out;

    dim3 block(32, 8, 1);         // 32 z-quads (lanes) x 8 y rows = 256 threads
    dim3 grid(NYc / 8, NXc, 1);   // (y tiles, x)
    rb_kernel<<<grid, block, 0, stream>>>(s, o);
}